// Round 3
// baseline (35.006 us; speedup 1.0000x reference)
//
#include <hip/hip_runtime.h>
#include <math.h>

// L1AttnSparse: bs=1, n_heads=8, width=64. coo rows canonical:
// r = t*dst_mxlen + c -> (dst=t, src=clamp(t-c,0,n_tok-1), cnt=c).
// Per (t,h): w_s = -(1/8) * sum_d |q[t,h,d] - k[s,h,d]|
//   denom = 1 + sum exp(w)  (sink logit 0; all w <= 0)
//   out[t,h,:] = sum m(t,s)*exp(w_s)*v[s,h,:] / denom
// where m(t,s) = multiplicity of src s in t's window:
//   s==0: m = max(0, dst_mxlen - t)   (clamp collapses c=t..31 onto s=0)
//   s>0 : m = (0 <= t-s < dst_mxlen) ? 1 : 0
//
// Wave layout: 4 heads x 16 lanes/head (float4 slice of width),
// 4 consecutive tokens per wave -> k/v loaded ONCE per (wave, src),
// reused for 4 destination tokens in registers (~3.7x VMEM cut).
// XCD-chunked swizzle keeps each XCD's token range L2-resident.

constexpr int H = 8;   // n_heads
constexpr int W = 64;  // width
constexpr int TPW = 4; // tokens per wave

__global__ __launch_bounds__(256) void l1attn_sparse_kernel(
    const float* __restrict__ v,
    const float* __restrict__ q,
    const float* __restrict__ k,
    const int*   __restrict__ p_dst_mxlen,
    const int*   __restrict__ p_use_softmax,
    float*       __restrict__ out,
    int n_tok)
{
    const int dst_mxlen = *p_dst_mxlen;     // uniform (=32)
    const int use_sm    = *p_use_softmax;   // uniform (=1)

    // XCD-aware chunked swizzle (bijective when gridDim.x % 8 == 0)
    int bid = blockIdx.x;
    if ((gridDim.x & 7) == 0) {
        const int chunk = gridDim.x >> 3;
        bid = (bid & 7) * chunk + (bid >> 3);
    }

    const int wid  = bid * (blockDim.x >> 6) + (threadIdx.x >> 6);
    const int lane = threadIdx.x & 63;

    const int tq = wid >> 1;            // token-quad index
    const int t0 = tq * TPW;
    if (t0 >= n_tok) return;
    const int h     = (wid & 1) * 4 + (lane >> 4);  // head 0..7
    const int dbase = (lane & 15) * 4;              // float4 slice

    // q for 4 tokens (clamped for tail safety)
    float4 qv[TPW];
    #pragma unroll
    for (int j = 0; j < TPW; ++j) {
        int t = t0 + j; t = t < n_tok ? t : n_tok - 1;
        qv[j] = *reinterpret_cast<const float4*>(q + (t * H + h) * W + dbase);
    }

    float4 acc[TPW];
    float  sump[TPW];
    #pragma unroll
    for (int j = 0; j < TPW; ++j) { acc[j] = {0.f,0.f,0.f,0.f}; sump[j] = 0.f; }

    int s_lo = t0 - (dst_mxlen - 1); s_lo = s_lo < 0 ? 0 : s_lo;
    const int s_hi = (t0 + TPW - 1) < (n_tok - 1) ? (t0 + TPW - 1) : (n_tok - 1);

    #pragma unroll 2
    for (int s = s_lo; s <= s_hi; ++s) {
        const int base = (s * H + h) * W + dbase;
        const float4 kv = *reinterpret_cast<const float4*>(k + base);
        const float4 vv = *reinterpret_cast<const float4*>(v + base);

        #pragma unroll
        for (int j = 0; j < TPW; ++j) {
            const int t = t0 + j;
            float a = fabsf(qv[j].x - kv.x) + fabsf(qv[j].y - kv.y) +
                      fabsf(qv[j].z - kv.z) + fabsf(qv[j].w - kv.w);
            // reduce across the 16 lanes of this head
            a += __shfl_xor(a, 1);
            a += __shfl_xor(a, 2);
            a += __shfl_xor(a, 4);
            a += __shfl_xor(a, 8);

            // multiplicity of this (t,s) pair under src clamping
            const int c = t - s;
            float m;
            if (s == 0) {                       // wave-uniform branch
                int mm = dst_mxlen - t;
                m = (float)(mm > 0 ? mm : 0);
            } else {
                m = (c >= 0 && c < dst_mxlen) ? 1.f : 0.f;
            }

            const float p = m * __expf(a * -0.125f);   // -1/sqrt(64)
            sump[j] += p;
            acc[j].x += p * vv.x; acc[j].y += p * vv.y;
            acc[j].z += p * vv.z; acc[j].w += p * vv.w;
        }
    }

    #pragma unroll
    for (int j = 0; j < TPW; ++j) {
        const int t = t0 + j;
        if (t < n_tok) {
            const float scale = use_sm ? 1.0f / (1.0f + sump[j]) : 1.0f;
            float4 o = {acc[j].x * scale, acc[j].y * scale,
                        acc[j].z * scale, acc[j].w * scale};
            *reinterpret_cast<float4*>(out + (t * H + h) * W + dbase) = o;
        }
    }
}

extern "C" void kernel_launch(void* const* d_in, const int* in_sizes, int n_in,
                              void* d_out, int out_size, void* d_ws, size_t ws_size,
                              hipStream_t stream) {
    const float* v   = (const float*)d_in[0];
    const float* q   = (const float*)d_in[1];
    const float* k   = (const float*)d_in[2];
    const int*   p_dst_mxlen = (const int*)d_in[4];
    const int*   p_use_sm    = (const int*)d_in[6];
    float* out = (float*)d_out;

    const int n_tok = in_sizes[1] / (H * W);   // q elements / (8*64)

    // waves = 2 per token-quad (head halves); 4 waves/block
    const int waves  = ((n_tok + TPW - 1) / TPW) * 2;
    const int blocks = (waves + 3) / 4;
    l1attn_sparse_kernel<<<blocks, 256, 0, stream>>>(
        v, q, k, p_dst_mxlen, p_use_sm, out, n_tok);
}

// Round 5
// 21.990 us; speedup vs baseline: 1.5919x; 1.5919x over previous
//
#include <hip/hip_runtime.h>
#include <math.h>

// L1AttnSparse: bs=1, n_heads=8, width=64. coo rows canonical:
// r = t*dst_mxlen + c -> (dst=t, src=clamp(t-c,0,n_tok-1), cnt=c).
// Per (t,h): w_s = -(1/8) * sum_d |q[t,h,d] - k[s,h,d]|
//   denom = 1 + sum exp(w)  (sink logit 0; all w <= 0)
//   out[t,h,:] = sum m(t,s)*exp(w_s)*v[s,h,:] / denom
// m(t,s): s==0 -> max(0, dst_mxlen - t); s>0 -> (0 <= t-s < dst_mxlen).
//
// Wave layout: 2 tokens x 4 heads, 16 lanes/head, float4/lane.
//   -> 4096 waves (16/CU) for latency hiding, ~2x k/v reuse.
// Reduction across the 16 lanes of a head done entirely with DPP
// (VALU pipe, no LDS): xor1/xor2 quad_perm, then half_mirror, mirror.

constexpr int H = 8;   // n_heads
constexpr int W = 64;  // width
constexpr int TPW = 2; // tokens per wave

template <int CTRL>
__device__ __forceinline__ float dpp_add(float x) {
    int xi = __builtin_bit_cast(int, x);
    int yi = __builtin_amdgcn_update_dpp(0, xi, CTRL, 0xf, 0xf, true);
    return x + __builtin_bit_cast(float, yi);
}

__device__ __forceinline__ float reduce16(float a) {
    a = dpp_add<0xB1>(a);   // quad_perm [1,0,3,2]  (xor 1)
    a = dpp_add<0x4E>(a);   // quad_perm [2,3,0,1]  (xor 2)
    a = dpp_add<0x141>(a);  // row_half_mirror      (combines quads in 8)
    a = dpp_add<0x140>(a);  // row_mirror           (combines octets in 16)
    return a;
}

__global__ __launch_bounds__(256) void l1attn_sparse_kernel(
    const float* __restrict__ v,
    const float* __restrict__ q,
    const float* __restrict__ k,
    const int*   __restrict__ p_dst_mxlen,
    const int*   __restrict__ p_use_softmax,
    float*       __restrict__ out,
    int n_tok)
{
    const int dst_mxlen = *p_dst_mxlen;     // uniform (=32)
    const int use_sm    = *p_use_softmax;   // uniform (=1)

    // XCD-aware chunked swizzle (bijective when gridDim.x % 8 == 0)
    int bid = blockIdx.x;
    if ((gridDim.x & 7) == 0) {
        const int chunk = gridDim.x >> 3;
        bid = (bid & 7) * chunk + (bid >> 3);
    }

    const int wid  = bid * (blockDim.x >> 6) + (threadIdx.x >> 6);
    const int lane = threadIdx.x & 63;

    const int pairIdx = wid >> 1;           // token-pair index
    const int t0 = pairIdx * TPW;
    if (t0 >= n_tok) return;
    const int h     = (wid & 1) * 4 + (lane >> 4);  // head 0..7
    const int dbase = (lane & 15) * 4;              // float4 slice of width

    // q for the 2 tokens (clamp tail)
    float4 qv[TPW];
    #pragma unroll
    for (int j = 0; j < TPW; ++j) {
        int t = t0 + j; t = t < n_tok ? t : n_tok - 1;
        qv[j] = *reinterpret_cast<const float4*>(q + (t * H + h) * W + dbase);
    }

    float4 acc[TPW];
    float  sump[TPW];
    #pragma unroll
    for (int j = 0; j < TPW; ++j) { acc[j] = {0.f,0.f,0.f,0.f}; sump[j] = 0.f; }

    int s_lo = t0 - (dst_mxlen - 1); s_lo = s_lo < 0 ? 0 : s_lo;
    const int s_hi = (t0 + TPW - 1) < (n_tok - 1) ? (t0 + TPW - 1) : (n_tok - 1);

    #pragma unroll 4
    for (int s = s_lo; s <= s_hi; ++s) {
        const int base = (s * H + h) * W + dbase;
        const float4 kv = *reinterpret_cast<const float4*>(k + base);
        const float4 vv = *reinterpret_cast<const float4*>(v + base);

        #pragma unroll
        for (int j = 0; j < TPW; ++j) {
            const int t = t0 + j;
            float a = fabsf(qv[j].x - kv.x) + fabsf(qv[j].y - kv.y) +
                      fabsf(qv[j].z - kv.z) + fabsf(qv[j].w - kv.w);
            a = reduce16(a);                 // sum over d within the head

            // multiplicity of this (t,s) pair under src clamping
            float m;
            if (s == 0) {
                int mm = dst_mxlen - t;
                m = (float)(mm > 0 ? mm : 0);
            } else {
                const int c = t - s;
                m = (c >= 0 && c < dst_mxlen) ? 1.f : 0.f;
            }

            const float p = m * __expf(a * -0.125f);   // -1/sqrt(64)
            sump[j] += p;
            acc[j].x += p * vv.x; acc[j].y += p * vv.y;
            acc[j].z += p * vv.z; acc[j].w += p * vv.w;
        }
    }

    #pragma unroll
    for (int j = 0; j < TPW; ++j) {
        const int t = t0 + j;
        if (t < n_tok) {
            const float scale = use_sm ? 1.0f / (1.0f + sump[j]) : 1.0f;
            float4 o = {acc[j].x * scale, acc[j].y * scale,
                        acc[j].z * scale, acc[j].w * scale};
            *reinterpret_cast<float4*>(out + (t * H + h) * W + dbase) = o;
        }
    }
}

extern "C" void kernel_launch(void* const* d_in, const int* in_sizes, int n_in,
                              void* d_out, int out_size, void* d_ws, size_t ws_size,
                              hipStream_t stream) {
    const float* v   = (const float*)d_in[0];
    const float* q   = (const float*)d_in[1];
    const float* k   = (const float*)d_in[2];
    const int*   p_dst_mxlen = (const int*)d_in[4];
    const int*   p_use_sm    = (const int*)d_in[6];
    float* out = (float*)d_out;

    const int n_tok = in_sizes[1] / (H * W);   // q elements / (8*64)

    // 2 waves (head halves) per token-pair; 4 waves per block
    const int pairs  = (n_tok + TPW - 1) / TPW;
    const int waves  = pairs * 2;
    const int blocks = (waves + 3) / 4;
    l1attn_sparse_kernel<<<blocks, 256, 0, stream>>>(
        v, q, k, p_dst_mxlen, p_use_sm, out, n_tok);
}

// Round 6
// 20.506 us; speedup vs baseline: 1.7071x; 1.0723x over previous
//
#include <hip/hip_runtime.h>
#include <math.h>

// L1AttnSparse: bs=1, n_heads=8, width=64. coo rows canonical:
// r = t*dst_mxlen + c -> (dst=t, src=clamp(t-c,0,n_tok-1), cnt=c).
// Per (t,h): w_s = -(1/8) * sum_d |q[t,h,d] - k[s,h,d]|
//   denom = 1 + sum exp(w)  (sink logit 0; all w <= 0)
//   out[t,h,:] = sum m(t,s)*exp(w_s)*v[s,h,:] / denom
// m(t,s): s==0 -> max(0, dst_mxlen - t); s>0 -> (0 <= t-s < dst_mxlen).
//
// Block = one token pair, 4 waves: sub = (headhalf, winhalf).
//   Each wave: 2 tokens x 4 heads, 16 lanes/head, float4/lane,
//   and HALF of the src window (~17 srcs) -> 8192 waves (100% occ target),
//   logical traffic unchanged (~270 MB, window halves disjoint).
// Partials (acc,sump) combined via 5KB conflict-free LDS + 1 barrier.
// Reduction over d within a head: 4 DPP adds (VALU pipe, no LDS).
// XCD-chunked swizzle keeps each XCD's token range L2-resident.

constexpr int H = 8;   // n_heads
constexpr int W = 64;  // width
constexpr int TPW = 2; // tokens per block

template <int CTRL>
__device__ __forceinline__ float dpp_add(float x) {
    int xi = __builtin_bit_cast(int, x);
    int yi = __builtin_amdgcn_update_dpp(0, xi, CTRL, 0xf, 0xf, true);
    return x + __builtin_bit_cast(float, yi);
}

__device__ __forceinline__ float reduce16(float a) {
    a = dpp_add<0xB1>(a);   // quad_perm [1,0,3,2]  (xor 1)
    a = dpp_add<0x4E>(a);   // quad_perm [2,3,0,1]  (xor 2)
    a = dpp_add<0x141>(a);  // row_half_mirror      (octet sum)
    a = dpp_add<0x140>(a);  // row_mirror           (16-lane sum)
    return a;
}

__global__ __launch_bounds__(256) void l1attn_sparse_kernel(
    const float* __restrict__ v,
    const float* __restrict__ q,
    const float* __restrict__ k,
    const int*   __restrict__ p_dst_mxlen,
    const int*   __restrict__ p_use_softmax,
    float*       __restrict__ out,
    int n_tok)
{
    const int dst_mxlen = *p_dst_mxlen;     // uniform (=32)
    const int use_sm    = *p_use_softmax;   // uniform (=1)

    // XCD-aware chunked swizzle (bijective when gridDim.x % 8 == 0)
    int bid = blockIdx.x;
    if ((gridDim.x & 7) == 0) {
        const int chunk = gridDim.x >> 3;
        bid = (bid & 7) * chunk + (bid >> 3);
    }

    const int sub  = threadIdx.x >> 6;      // wave in block: 0..3
    const int lane = threadIdx.x & 63;
    const int headhalf = sub >> 1;          // 0: heads 0-3, 1: heads 4-7
    const int winhalf  = sub & 1;           // which half of the src window

    const int t0 = bid * TPW;
    if (t0 >= n_tok) return;

    const int h     = headhalf * 4 + (lane >> 4);
    const int dbase = (lane & 15) * 4;      // float4 slice of width

    // q for the 2 tokens (clamp tail)
    float4 qv[TPW];
    #pragma unroll
    for (int j = 0; j < TPW; ++j) {
        int t = t0 + j; t = t < n_tok ? t : n_tok - 1;
        qv[j] = *reinterpret_cast<const float4*>(q + (t * H + h) * W + dbase);
    }

    float4 acc[TPW];
    float  sump[TPW];
    #pragma unroll
    for (int j = 0; j < TPW; ++j) { acc[j] = {0.f,0.f,0.f,0.f}; sump[j] = 0.f; }

    // full window for this pair, then split across winhalf waves
    int s_lo = t0 - (dst_mxlen - 1); s_lo = s_lo < 0 ? 0 : s_lo;
    const int s_hi = (t0 + TPW - 1) < (n_tok - 1) ? (t0 + TPW - 1) : (n_tok - 1);
    const int len  = s_hi - s_lo + 1;
    const int half = (len + 1) >> 1;
    const int my_lo = winhalf ? s_lo + half : s_lo;
    const int my_hi = winhalf ? s_hi       : s_lo + half - 1;

    #pragma unroll 4
    for (int s = my_lo; s <= my_hi; ++s) {
        const int base = (s * H + h) * W + dbase;
        const float4 kv = *reinterpret_cast<const float4*>(k + base);
        const float4 vv = *reinterpret_cast<const float4*>(v + base);

        #pragma unroll
        for (int j = 0; j < TPW; ++j) {
            const int t = t0 + j;
            float a = fabsf(qv[j].x - kv.x) + fabsf(qv[j].y - kv.y) +
                      fabsf(qv[j].z - kv.z) + fabsf(qv[j].w - kv.w);
            a = reduce16(a);                 // sum over d within the head

            // multiplicity of this (t,s) pair under src clamping
            float m;
            if (s == 0) {
                int mm = dst_mxlen - t;
                m = (float)(mm > 0 ? mm : 0);
            } else {
                const int c = t - s;
                m = (c >= 0 && c < dst_mxlen) ? 1.f : 0.f;
            }

            const float p = m * __expf(a * -0.125f);   // -1/sqrt(64)
            sump[j] += p;
            acc[j].x += p * vv.x; acc[j].y += p * vv.y;
            acc[j].z += p * vv.z; acc[j].w += p * vv.w;
        }
    }

    // combine winhalf partials through LDS (conflict-free: lane-contiguous)
    __shared__ float lds[2][TPW][5][64];    // [headhalf][token][acc4+sump][lane]
    if (winhalf == 1) {
        #pragma unroll
        for (int j = 0; j < TPW; ++j) {
            lds[headhalf][j][0][lane] = acc[j].x;
            lds[headhalf][j][1][lane] = acc[j].y;
            lds[headhalf][j][2][lane] = acc[j].z;
            lds[headhalf][j][3][lane] = acc[j].w;
            lds[headhalf][j][4][lane] = sump[j];
        }
    }
    __syncthreads();
    if (winhalf == 0) {
        #pragma unroll
        for (int j = 0; j < TPW; ++j) {
            acc[j].x += lds[headhalf][j][0][lane];
            acc[j].y += lds[headhalf][j][1][lane];
            acc[j].z += lds[headhalf][j][2][lane];
            acc[j].w += lds[headhalf][j][3][lane];
            sump[j]  += lds[headhalf][j][4][lane];

            const int t = t0 + j;
            if (t < n_tok) {
                const float scale = use_sm ? 1.0f / (1.0f + sump[j]) : 1.0f;
                float4 o = {acc[j].x * scale, acc[j].y * scale,
                            acc[j].z * scale, acc[j].w * scale};
                *reinterpret_cast<float4*>(out + (t * H + h) * W + dbase) = o;
            }
        }
    }
}

extern "C" void kernel_launch(void* const* d_in, const int* in_sizes, int n_in,
                              void* d_out, int out_size, void* d_ws, size_t ws_size,
                              hipStream_t stream) {
    const float* v   = (const float*)d_in[0];
    const float* q   = (const float*)d_in[1];
    const float* k   = (const float*)d_in[2];
    const int*   p_dst_mxlen = (const int*)d_in[4];
    const int*   p_use_sm    = (const int*)d_in[6];
    float* out = (float*)d_out;

    const int n_tok = in_sizes[1] / (H * W);   // q elements / (8*64)

    // one block (4 waves) per token pair
    const int blocks = (n_tok + TPW - 1) / TPW;
    l1attn_sparse_kernel<<<blocks, 256, 0, stream>>>(
        v, q, k, p_dst_mxlen, p_use_sm, out, n_tok);
}